// Round 1
// baseline (13647.133 us; speedup 1.0000x reference)
//
#include <hip/hip_runtime.h>
#include <stdint.h>

// Fixed 8x8x8 grid complex: nV=512, nE=2863, nT=4410, nTet=2058, nS=9843.
// Capacities (compile-time):
#define MAX_S 10240
#define MAX_E 3072
#define MAX_T 4608
#define MAX_V 1024
#define EW    48   // u64 words per reduction row >= ceil(MAX_E/64)

__device__ float g_f[MAX_S];                 // filtration value per simplex (min over verts)
__device__ int   g_cnt[4];                   // simplex count per dimension
__device__ int   g_erank[MAX_E];             // edge local idx -> rank (f desc, idx asc)
__device__ float g_ef[MAX_E];                // f by edge rank
__device__ int   g_eorder[MAX_E];            // edge rank -> local idx
__device__ int   g_trank[MAX_T];             // tri local idx -> rank
__device__ float g_tf[MAX_T];                // f by tri rank
__device__ unsigned long long g_rows[(size_t)MAX_T * EW];  // boundary rows over edge-rank bits
__device__ float g_loss0;
__device__ int   g_parent[MAX_V];
__device__ float g_birth[MAX_V];

__global__ void k_init() {
  size_t i = (size_t)blockIdx.x * blockDim.x + threadIdx.x;
  size_t tot = (size_t)MAX_T * EW;
  for (size_t k = i; k < tot; k += (size_t)gridDim.x * blockDim.x)
    g_rows[k] = 0ull;
  if (i < 4) g_cnt[i] = 0;
  if (i == 0) g_loss0 = 0.f;
}

__global__ void k_f(const float* __restrict__ beta, const int* __restrict__ sv,
                    const int* __restrict__ sd, int nS) {
  int i = blockIdx.x * blockDim.x + threadIdx.x;
  if (i >= nS) return;
  float f = beta[sv[4 * i]];
  f = fminf(f, beta[sv[4 * i + 1]]);
  f = fminf(f, beta[sv[4 * i + 2]]);
  f = fminf(f, beta[sv[4 * i + 3]]);
  g_f[i] = f;
  int d = sd[i];
  if (d >= 0 && d < 4) atomicAdd(&g_cnt[d], 1);
}

// Rank edges by (f desc, idx asc) via counting; O(nE^2) comparisons, parallel.
__global__ void k_erank(int nV) {
  int nE = g_cnt[1];
  int i = blockIdx.x * blockDim.x + threadIdx.x;
  if (i >= nE) return;
  float fi = g_f[nV + i];
  int r = 0;
  for (int j = 0; j < nE; ++j) {
    float fj = g_f[nV + j];
    r += (fj > fi) || (fj == fi && j < i);
  }
  g_erank[i] = r;
  g_eorder[r] = i;
  g_ef[r] = fi;
}

__global__ void k_trank(int nV) {
  int nE = g_cnt[1], nT = g_cnt[2];
  int base = nV + nE;
  int i = blockIdx.x * blockDim.x + threadIdx.x;
  if (i >= nT) return;
  float fi = g_f[base + i];
  int r = 0;
  for (int j = 0; j < nT; ++j) {
    float fj = g_f[base + j];
    r += (fj > fi) || (fj == fi && j < i);
  }
  g_trank[i] = r;
  g_tf[r] = fi;
}

__device__ int uf_find(int x) {
  int r = x;
  while (g_parent[r] != r) r = g_parent[r];
  while (g_parent[x] != r) { int nx = g_parent[x]; g_parent[x] = r; x = nx; }
  return r;
}

// Dim-0 persistence: Kruskal union-find with elder rule over edges in f-desc order.
__global__ void k_uf(const int* __restrict__ sv, int nV) {
  if (threadIdx.x != 0 || blockIdx.x != 0) return;
  int nE = g_cnt[1];
  for (int v = 0; v < nV; ++v) { g_parent[v] = v; g_birth[v] = g_f[v]; }
  float loss = 0.f;
  for (int k = 0; k < nE; ++k) {
    int e = g_eorder[k];
    float fe = g_ef[k];
    int u = sv[(size_t)(nV + e) * 4];
    int v = sv[(size_t)(nV + e) * 4 + 1];
    int ru = uf_find(u), rv = uf_find(v);
    if (ru == rv) continue;                 // cycle edge -> dim-1 birth, handled by reduction
    float bu = g_birth[ru], bv = g_birth[rv];
    loss += fminf(bu, bv) - fe;             // younger component dies
    if (bu >= bv) g_parent[rv] = ru; else g_parent[ru] = rv;
  }
  g_loss0 = loss;
}

// Scatter each triangle's 3 boundary edges into its row (at its sorted position).
// bnd_face layout (from reference construction): edges' 2*nE entries, then tris' 3*nT.
__global__ void k_scatter(const int* __restrict__ bf, int nV) {
  int nE = g_cnt[1], nT = g_cnt[2];
  int t = blockIdx.x * blockDim.x + threadIdx.x;
  if (t >= nT) return;
  int r = g_trank[t];
  size_t base = (size_t)2 * nE + (size_t)3 * t;
  for (int j = 0; j < 3; ++j) {
    int er = g_erank[bf[base + j] - nV];
    atomicOr(&g_rows[(size_t)r * EW + (er >> 6)], 1ull << (er & 63));
  }
}

// Dim-1 persistence: standard reduction of the triangle/edge boundary block.
// One wavefront; lane w holds 64-bit word w of the active row.
__global__ void __launch_bounds__(64) k_reduce(float* __restrict__ out) {
  __shared__ int spiv[MAX_E];
  int lane = threadIdx.x;
  int nE = g_cnt[1], nT = g_cnt[2];
  for (int i = lane; i < nE; i += 64) spiv[i] = -1;
  __syncthreads();
  float sum = 0.f, mx = 0.f;
  for (int r = 0; r < nT; ++r) {
    unsigned long long w = (lane < EW) ? g_rows[(size_t)r * EW + lane] : 0ull;
    for (;;) {
      int hb = w ? ((lane << 6) + 63 - __clzll(w)) : -1;
      int low = hb;
      #pragma unroll
      for (int off = 32; off; off >>= 1) {
        int o = __shfl_xor(low, off, 64);
        low = low > o ? low : o;
      }
      if (low < 0) break;                    // row reduced to zero (dim-2 birth)
      int p = spiv[low];
      if (p < 0) {
        if (lane == 0) spiv[low] = r;        // claim pivot: edge 'low' killed by tri r
        float len = g_ef[low] - g_tf[r];     // birth - death >= 0
        sum += len;
        mx = fmaxf(mx, len);
        break;
      }
      w ^= (lane < EW) ? g_rows[(size_t)p * EW + lane] : 0ull;
    }
    if (lane < EW) g_rows[(size_t)r * EW + lane] = w;
    __syncthreads();                         // make stored row + piv visible to next iter
  }
  if (lane == 0) out[0] = g_loss0 + sum - mx;  // loss1 = sum - max
}

extern "C" void kernel_launch(void* const* d_in, const int* in_sizes, int n_in,
                              void* d_out, int out_size, void* d_ws, size_t ws_size,
                              hipStream_t stream) {
  const float* beta = (const float*)d_in[0];
  const int*   sv   = (const int*)d_in[1];
  const int*   sd   = (const int*)d_in[2];
  const int*   bf   = (const int*)d_in[4];
  float* out = (float*)d_out;

  int nV = in_sizes[0];
  int nS = in_sizes[2];

  k_init<<<864, 256, 0, stream>>>();
  k_f<<<(nS + 255) / 256, 256, 0, stream>>>(beta, sv, sd, nS);
  k_erank<<<(MAX_E + 255) / 256, 256, 0, stream>>>(nV);
  k_trank<<<(MAX_T + 255) / 256, 256, 0, stream>>>(nV);
  k_uf<<<1, 1, 0, stream>>>(sv, nV);
  k_scatter<<<(MAX_T + 255) / 256, 256, 0, stream>>>(bf, nV);
  k_reduce<<<1, 64, 0, stream>>>(out);
}

// Round 2
// 3513.263 us; speedup vs baseline: 3.8845x; 3.8845x over previous
//
#include <hip/hip_runtime.h>
#include <stdint.h>

// Fixed 8x8x8 grid complex: nV=512, nE=2863, nT=4410, nTet=2058, nS=9843.
#define MAX_S 10240
#define MAX_E 3072
#define MAX_T 4608
#define MAX_V 1024
#define EW    48   // u64 words per reduction row >= ceil(MAX_E/64)
#define INF_I 0x7fffffff

__device__ float g_f[MAX_S];                 // filtration value per simplex (min over verts)
__device__ int   g_cnt[4];                   // simplex count per dimension
__device__ int   g_erank[MAX_E];             // edge local idx -> rank (f desc, idx asc)
__device__ float g_ef[MAX_E];                // f by edge rank
__device__ int   g_eorder[MAX_E];            // edge rank -> local idx
__device__ int   g_trank[MAX_T];             // tri local idx -> rank
__device__ float g_tf[MAX_T];                // f by tri rank
__device__ unsigned long long g_rows[(size_t)MAX_T * EW];  // boundary rows, edge-rank bits
__device__ float g_loss0;

__global__ void k_init() {
  size_t i = (size_t)blockIdx.x * blockDim.x + threadIdx.x;
  size_t tot = (size_t)MAX_T * EW;
  for (size_t k = i; k < tot; k += (size_t)gridDim.x * blockDim.x)
    g_rows[k] = 0ull;
  if (i < 4) g_cnt[i] = 0;
}

__global__ void k_f(const float* __restrict__ beta, const int* __restrict__ sv,
                    const int* __restrict__ sd, int nS) {
  int i = blockIdx.x * blockDim.x + threadIdx.x;
  if (i >= nS) return;
  float f = beta[sv[4 * i]];
  f = fminf(f, beta[sv[4 * i + 1]]);
  f = fminf(f, beta[sv[4 * i + 2]]);
  f = fminf(f, beta[sv[4 * i + 3]]);
  g_f[i] = f;
  int d = sd[i];
  if (d >= 0 && d < 4) atomicAdd(&g_cnt[d], 1);
}

// Rank edges by (f desc, idx asc) via counting; parallel O(nE^2) compares.
__global__ void k_erank(int nV) {
  int nE = g_cnt[1];
  int i = blockIdx.x * blockDim.x + threadIdx.x;
  if (i >= nE) return;
  float fi = g_f[nV + i];
  int r = 0;
  for (int j = 0; j < nE; ++j) {
    float fj = g_f[nV + j];
    r += (fj > fi) || (fj == fi && j < i);
  }
  g_erank[i] = r;
  g_eorder[r] = i;
  g_ef[r] = fi;
}

__global__ void k_trank(int nV) {
  int nE = g_cnt[1], nT = g_cnt[2];
  int base = nV + nE;
  int i = blockIdx.x * blockDim.x + threadIdx.x;
  if (i >= nT) return;
  float fi = g_f[base + i];
  int r = 0;
  for (int j = 0; j < nT; ++j) {
    float fj = g_f[base + j];
    r += (fj > fi) || (fj == fi && j < i);
  }
  g_trank[i] = r;
  g_tf[r] = fi;
}

// Dim-0 loss closed form: loss0 = sum_v f(v) - max_v f(v) - W(max spanning tree).
// Kruskal over rank-ordered edges, union-find entirely in LDS.
__global__ void __launch_bounds__(256) k_uf(const int* __restrict__ sv, int nV) {
  __shared__ int   par[MAX_V];
  __shared__ int   eu[MAX_E];
  __shared__ int   ev2[MAX_E];
  __shared__ float sef[MAX_E];
  __shared__ float s_sum[4];
  __shared__ float s_max[4];
  int tid = threadIdx.x;
  int nE = g_cnt[1];
  for (int v = tid; v < nV; v += 256) par[v] = v;
  for (int k = tid; k < nE; k += 256) {
    int e = g_eorder[k];
    eu[k]  = sv[(size_t)(nV + e) * 4];
    ev2[k] = sv[(size_t)(nV + e) * 4 + 1];
    sef[k] = g_ef[k];
  }
  float s = 0.f, m = -3.0e38f;
  for (int v = tid; v < nV; v += 256) { float fv = g_f[v]; s += fv; m = fmaxf(m, fv); }
  #pragma unroll
  for (int off = 32; off; off >>= 1) {
    s += __shfl_xor(s, off, 64);
    m = fmaxf(m, __shfl_xor(m, off, 64));
  }
  int lane = tid & 63, wave = tid >> 6;
  if (lane == 0) { s_sum[wave] = s; s_max[wave] = m; }
  __syncthreads();
  if (tid == 0) {
    float S = 0.f, M = -3.0e38f;
    for (int i = 0; i < 4; ++i) { S += s_sum[i]; M = fmaxf(M, s_max[i]); }
    float W = 0.f;
    for (int k = 0; k < nE; ++k) {
      int a = eu[k], b = ev2[k];
      while (par[a] != a) { par[a] = par[par[a]]; a = par[a]; }
      while (par[b] != b) { par[b] = par[par[b]]; b = par[b]; }
      if (a != b) { W += sef[k]; par[a] = b; }
    }
    g_loss0 = S - M - W;
  }
}

// Scatter each triangle's 3 boundary edges into its row (at its sorted position).
__global__ void k_scatter(const int* __restrict__ bf, int nV) {
  int nE = g_cnt[1], nT = g_cnt[2];
  int t = blockIdx.x * blockDim.x + threadIdx.x;
  if (t >= nT) return;
  int r = g_trank[t];
  size_t base = (size_t)2 * nE + (size_t)3 * t;
  for (int j = 0; j < 3; ++j) {
    int er = g_erank[bf[base + j] - nV];
    atomicOr(&g_rows[(size_t)r * EW + (er >> 6)], 1ull << (er & 63));
  }
}

// Dim-1 persistence: lock-free parallel reduction, 16 waves in one block.
// Pairing-uniqueness: any schedule of "row j ^= row i, i<j" that terminates
// with all-distinct lows yields the canonical pairing. Claims by atomicMin
// (smaller sorted row wins). frozen[] (set in a read-only stage) guarantees
// stage-2 XOR chains only read rows whose owners are idle this pass.
__global__ void __launch_bounds__(1024) k_reduce(float* __restrict__ out) {
  __shared__ int spiv[MAX_E];
  __shared__ int lowA[MAX_T];
  __shared__ unsigned char frozen[MAX_T];
  __shared__ int activeCnt;
  __shared__ float ssum[16];
  __shared__ float smax[16];

  int tid = threadIdx.x;
  int lane = tid & 63;
  int wave = tid >> 6;
  int nE = g_cnt[1], nT = g_cnt[2];

  for (int i = tid; i < nE; i += 1024) spiv[i] = INF_I;
  if (tid == 0) activeCnt = 0;
  __syncthreads();

  // initial lows + claims
  for (int r = wave; r < nT; r += 16) {
    unsigned long long w = (lane < EW) ? g_rows[(size_t)r * EW + lane] : 0ull;
    int low = w ? ((lane << 6) + 63 - __clzll(w)) : -1;
    #pragma unroll
    for (int off = 32; off; off >>= 1) {
      int o = __shfl_xor(low, off, 64);
      low = low > o ? low : o;
    }
    if (lane == 0) {
      lowA[r] = low;
      if (low >= 0) atomicMin(&spiv[low], r);
    }
  }
  __syncthreads();

  for (;;) {
    // stage 1 (read-only): freeze decision
    for (int r = tid; r < nT; r += 1024) {
      int l = lowA[r];
      bool st = (l < 0) || (spiv[l] == r);
      frozen[r] = st ? 1 : 0;
      if (!st) atomicAdd(&activeCnt, 1);
    }
    __syncthreads();
    int n = activeCnt;
    __syncthreads();               // everyone reads n before reset
    if (n == 0) break;
    if (tid == 0) activeCnt = 0;
    // stage 2: losers XOR-chain through frozen winners only
    for (int r = wave; r < nT; r += 16) {
      if (frozen[r]) continue;
      int l = lowA[r];             // >=0 and spiv[l] < r
      unsigned long long w = (lane < EW) ? g_rows[(size_t)r * EW + lane] : 0ull;
      for (;;) {
        int p = spiv[l];           // p < r
        if (!frozen[p]) break;     // winner busy this pass -> retry next pass
        w ^= (lane < EW) ? g_rows[(size_t)p * EW + lane] : 0ull;
        int low = w ? ((lane << 6) + 63 - __clzll(w)) : -1;
        #pragma unroll
        for (int off = 32; off; off >>= 1) {
          int o = __shfl_xor(low, off, 64);
          low = low > o ? low : o;
        }
        l = low;
        if (l < 0) break;          // reduced to zero
        int old = atomicMin(&spiv[l], r);
        if (old > r) break;        // claimed; evictee reacts next pass
        // old < r: smaller claimant exists; loop and maybe chain again
      }
      if (lane < EW) g_rows[(size_t)r * EW + lane] = w;
      if (lane == 0) lowA[r] = l;
    }
    __syncthreads();
  }

  // epilogue: loss1 = sum(len) - max(len) over claimed pivots
  float sum = 0.f, mx = 0.f;
  for (int l = tid; l < nE; l += 1024) {
    int r = spiv[l];
    if (r != INF_I) {
      float len = g_ef[l] - g_tf[r];
      sum += len;
      mx = fmaxf(mx, len);
    }
  }
  #pragma unroll
  for (int off = 32; off; off >>= 1) {
    sum += __shfl_xor(sum, off, 64);
    mx = fmaxf(mx, __shfl_xor(mx, off, 64));
  }
  if (lane == 0) { ssum[wave] = sum; smax[wave] = mx; }
  __syncthreads();
  if (tid == 0) {
    float S = 0.f, M = 0.f;
    for (int i = 0; i < 16; ++i) { S += ssum[i]; M = fmaxf(M, smax[i]); }
    out[0] = g_loss0 + S - M;
  }
}

extern "C" void kernel_launch(void* const* d_in, const int* in_sizes, int n_in,
                              void* d_out, int out_size, void* d_ws, size_t ws_size,
                              hipStream_t stream) {
  const float* beta = (const float*)d_in[0];
  const int*   sv   = (const int*)d_in[1];
  const int*   sd   = (const int*)d_in[2];
  const int*   bf   = (const int*)d_in[4];
  float* out = (float*)d_out;

  int nV = in_sizes[0];
  int nS = in_sizes[2];

  k_init<<<864, 256, 0, stream>>>();
  k_f<<<(nS + 255) / 256, 256, 0, stream>>>(beta, sv, sd, nS);
  k_erank<<<(MAX_E + 255) / 256, 256, 0, stream>>>(nV);
  k_trank<<<(MAX_T + 255) / 256, 256, 0, stream>>>(nV);
  k_uf<<<1, 256, 0, stream>>>(sv, nV);
  k_scatter<<<(MAX_T + 255) / 256, 256, 0, stream>>>(bf, nV);
  k_reduce<<<1, 1024, 0, stream>>>(out);
}

// Round 3
// 1288.436 us; speedup vs baseline: 10.5920x; 2.7268x over previous
//
#include <hip/hip_runtime.h>
#include <stdint.h>

// Fixed 8x8x8 grid complex: nV=512, nE=2863, nT=4410, nTet=2058, nS=9843.
#define MAX_S 10240
#define MAX_E 3072
#define MAX_T 4608
#define MAX_V 1024
#define EW    48   // u64 words per reduction row >= ceil(MAX_E/64)
#define INF_I 0x7fffffff

__device__ float g_f[MAX_S];                 // filtration value per simplex (min over verts)
__device__ int   g_cnt[4];                   // simplex count per dimension
__device__ int   g_erank[MAX_E];             // edge local idx -> rank (f desc, idx asc)
__device__ float g_ef[MAX_E];                // f by edge rank
__device__ int   g_trank[MAX_T];             // tri local idx -> rank
__device__ float g_tf[MAX_T];                // f by tri rank
__device__ unsigned long long g_rows[(size_t)MAX_T * EW];  // boundary rows, edge-rank bits
__device__ float g_loss0;

__global__ void k_init() {
  size_t i = (size_t)blockIdx.x * blockDim.x + threadIdx.x;
  size_t tot = (size_t)MAX_T * EW;
  for (size_t k = i; k < tot; k += (size_t)gridDim.x * blockDim.x)
    g_rows[k] = 0ull;
  if (i < 4) g_cnt[i] = 0;
}

__global__ void k_f(const float* __restrict__ beta, const int* __restrict__ sv,
                    const int* __restrict__ sd, int nS) {
  int i = blockIdx.x * blockDim.x + threadIdx.x;
  if (i >= nS) return;
  float f = beta[sv[4 * i]];
  f = fminf(f, beta[sv[4 * i + 1]]);
  f = fminf(f, beta[sv[4 * i + 2]]);
  f = fminf(f, beta[sv[4 * i + 3]]);
  g_f[i] = f;
  int d = sd[i];
  if (d >= 0 && d < 4) atomicAdd(&g_cnt[d], 1);
}

// Rank edges by (f desc, idx asc) via counting; f staged in LDS (broadcast reads).
__global__ void __launch_bounds__(256) k_erank(int nV) {
  __shared__ float sf[MAX_E];
  int nE = g_cnt[1];
  for (int j = threadIdx.x; j < nE; j += 256) sf[j] = g_f[nV + j];
  __syncthreads();
  int i = blockIdx.x * blockDim.x + threadIdx.x;
  if (i >= nE) return;
  float fi = sf[i];
  int r = 0;
  for (int j = 0; j < nE; ++j) {
    float fj = sf[j];
    r += (fj > fi) || (fj == fi && j < i);
  }
  g_erank[i] = r;
  g_ef[r] = fi;
}

__global__ void __launch_bounds__(256) k_trank(int nV) {
  __shared__ float sf[MAX_T];
  int nE = g_cnt[1], nT = g_cnt[2];
  int base = nV + nE;
  for (int j = threadIdx.x; j < nT; j += 256) sf[j] = g_f[base + j];
  __syncthreads();
  int i = blockIdx.x * blockDim.x + threadIdx.x;
  if (i >= nT) return;
  float fi = sf[i];
  int r = 0;
  for (int j = 0; j < nT; ++j) {
    float fj = sf[j];
    r += (fj > fi) || (fj == fi && j < i);
  }
  g_trank[i] = r;
  g_tf[r] = fi;
}

// Dim-0 loss closed form: loss0 = sum_v f(v) - max_v f(v) - W(max spanning tree).
// W via parallel Boruvka in LDS over strict keys (f bits, edge idx).
// All maximum spanning trees share the same weight multiset, so W is unique.
__global__ void __launch_bounds__(256) k_uf(const int* __restrict__ sv, int nV) {
  __shared__ int par[MAX_V];
  __shared__ unsigned long long cand[MAX_V];
  __shared__ int hookTo[MAX_V];
  __shared__ int eu[MAX_E], ev2[MAX_E];
  __shared__ float efv[MAX_E];
  __shared__ unsigned int ekey[MAX_E];
  __shared__ float aS[4], aM[4], aW[4];
  __shared__ int nRoots;
  int tid = threadIdx.x;
  int nE = g_cnt[1];
  for (int v = tid; v < nV; v += 256) par[v] = v;
  for (int e = tid; e < nE; e += 256) {
    eu[e]  = sv[(size_t)(nV + e) * 4];
    ev2[e] = sv[(size_t)(nV + e) * 4 + 1];
    float fe = g_f[nV + e];
    efv[e] = fe;
    unsigned int b = __float_as_uint(fe);
    ekey[e] = (b & 0x80000000u) ? ~b : (b | 0x80000000u);  // orderable
  }
  float s = 0.f, m = -3.0e38f;
  for (int v = tid; v < nV; v += 256) { float fv = g_f[v]; s += fv; m = fmaxf(m, fv); }
  float W = 0.f;
  __syncthreads();
  for (int phase = 0; phase < 12; ++phase) {
    for (int v = tid; v < nV; v += 256) cand[v] = 0ull;
    __syncthreads();
    for (int e = tid; e < nE; e += 256) {
      int ra = eu[e];  while (par[ra] != ra) ra = par[ra];
      int rb = ev2[e]; while (par[rb] != rb) rb = par[rb];
      if (ra != rb) {
        unsigned long long key = ((unsigned long long)ekey[e] << 32) | (unsigned int)e;
        atomicMax(&cand[ra], key);
        atomicMax(&cand[rb], key);
      }
    }
    __syncthreads();
    for (int v = tid; v < nV; v += 256) {
      int t = -1;
      unsigned long long cv = cand[v];
      if (par[v] == v && cv) {
        int e = (int)(cv & 0xffffffffu);
        int ra = eu[e];  while (par[ra] != ra) ra = par[ra];
        int rb = ev2[e]; while (par[rb] != rb) rb = par[rb];
        int other = (ra == v) ? rb : ra;
        // distinct-edge 2-cycles are impossible (key maximality); same-edge: smaller hooks
        if (cand[other] != cv || v < other) t = other;
      }
      hookTo[v] = t;
    }
    __syncthreads();
    for (int v = tid; v < nV; v += 256) {
      int t = hookTo[v];
      if (t >= 0) { par[v] = t; W += efv[(int)(cand[v] & 0xffffffffu)]; }
    }
    __syncthreads();
    for (int it = 0; it < 6; ++it) {
      for (int v = tid; v < nV; v += 256) { int p = par[v]; int gp = par[p]; if (p != gp) par[v] = gp; }
      __syncthreads();
    }
    if (tid == 0) nRoots = 0;
    __syncthreads();
    int loc = 0;
    for (int v = tid; v < nV; v += 256) loc += (par[v] == v);
    atomicAdd(&nRoots, loc);
    __syncthreads();
    if (nRoots <= 1) break;
    __syncthreads();
  }
  int lane = tid & 63, wave = tid >> 6;
  #pragma unroll
  for (int off = 32; off; off >>= 1) {
    s += __shfl_xor(s, off, 64);
    m = fmaxf(m, __shfl_xor(m, off, 64));
    W += __shfl_xor(W, off, 64);
  }
  if (lane == 0) { aS[wave] = s; aM[wave] = m; aW[wave] = W; }
  __syncthreads();
  if (tid == 0) {
    float S = 0.f, M = -3.0e38f, WW = 0.f;
    for (int i = 0; i < 4; ++i) { S += aS[i]; M = fmaxf(M, aM[i]); WW += aW[i]; }
    g_loss0 = S - M - WW;
  }
}

// Scatter each triangle's 3 boundary edges into its row (at its sorted position).
__global__ void k_scatter(const int* __restrict__ bf, int nV) {
  int nE = g_cnt[1], nT = g_cnt[2];
  int t = blockIdx.x * blockDim.x + threadIdx.x;
  if (t >= nT) return;
  int r = g_trank[t];
  size_t base = (size_t)2 * nE + (size_t)3 * t;
  for (int j = 0; j < 3; ++j) {
    int er = g_erank[bf[base + j] - nV];
    atomicOr(&g_rows[(size_t)r * EW + (er >> 6)], 1ull << (er & 63));
  }
}

// Dim-1 persistence: lock-free parallel reduction with active work lists.
// Per pass: stamp active rows; each active row XOR-chains through UNSTAMPED
// winners (their rows are static this pass). Blocked rows and evicted owners
// form the next pass's list. Smallest active row's winner is never stamped,
// so every pass settles at least one row -> terminates at canonical pairing.
__global__ void __launch_bounds__(1024) k_reduce(float* __restrict__ out) {
  __shared__ int spiv[MAX_E];       // 12KB  edge-rank -> owning row (or INF)
  __shared__ int lowA[MAX_T];       // 18KB
  __shared__ int stamp[MAX_T];      // 18KB  epoch of last activity
  __shared__ int lists[2][MAX_T];   // 36KB  ping-pong active lists
  __shared__ int cnts[2];
  __shared__ int workIdx;
  __shared__ float ssum[16], smax[16];

  int tid = threadIdx.x;
  int lane = tid & 63;
  int wave = tid >> 6;
  int nE = g_cnt[1], nT = g_cnt[2];

  for (int i = tid; i < nE; i += 1024) spiv[i] = INF_I;
  for (int r = tid; r < nT; r += 1024) stamp[r] = -1;
  if (tid == 0) { cnts[0] = 0; cnts[1] = 0; }
  __syncthreads();

  // initial lows + claims (two rows in flight per wave to hide L2 latency)
  for (int r = wave; r < nT; r += 32) {
    int r2 = r + 16;
    unsigned long long w1 = (lane < EW) ? g_rows[(size_t)r * EW + lane] : 0ull;
    unsigned long long w2 = (r2 < nT && lane < EW) ? g_rows[(size_t)r2 * EW + lane] : 0ull;
    unsigned long long m1 = __ballot(w1 != 0ull);
    int hb1 = (lane << 6) + 63 - __clzll(w1 | 1ull);
    int low1 = -1;
    if (m1) low1 = __shfl(hb1, 63 - __clzll(m1));
    if (lane == 0) { lowA[r] = low1; if (low1 >= 0) atomicMin(&spiv[low1], r); }
    if (r2 < nT) {
      unsigned long long m2 = __ballot(w2 != 0ull);
      int hb2 = (lane << 6) + 63 - __clzll(w2 | 1ull);
      int low2 = -1;
      if (m2) low2 = __shfl(hb2, 63 - __clzll(m2));
      if (lane == 0) { lowA[r2] = low2; if (low2 >= 0) atomicMin(&spiv[low2], r2); }
    }
  }
  __syncthreads();
  // initial active list = rows that lost their claim
  for (int r = tid; r < nT; r += 1024) {
    int l = lowA[r];
    if (l >= 0 && spiv[l] != r) { int q = atomicAdd(&cnts[0], 1); lists[0][q] = r; }
  }
  __syncthreads();

  int pass = 0;
  int cnt = cnts[0];
  while (cnt > 0 && pass < 50000) {
    int cur = pass & 1, nxt = cur ^ 1;
    if (tid == 0) { cnts[nxt] = 0; workIdx = 0; }
    for (int i = tid; i < cnt; i += 1024) stamp[lists[cur][i]] = pass;
    __syncthreads();
    for (;;) {
      int idx = 0;
      if (lane == 0) idx = atomicAdd(&workIdx, 1);
      idx = __shfl(idx, 0);
      if (idx >= cnt) break;
      int r = lists[cur][idx];
      int l = lowA[r];                       // >= 0 for every listed row
      unsigned long long w = 0ull;
      bool loaded = false, modified = false;
      for (;;) {
        int p = spiv[l];                     // p < r always
        if (stamp[p] == pass) {              // winner busy this pass -> retry next
          if (lane == 0) { int q = atomicAdd(&cnts[nxt], 1); lists[nxt][q] = r; }
          break;
        }
        if (!loaded) { w = (lane < EW) ? g_rows[(size_t)r * EW + lane] : 0ull; loaded = true; }
        w ^= (lane < EW) ? g_rows[(size_t)p * EW + lane] : 0ull;
        modified = true;
        unsigned long long msk = __ballot(w != 0ull);
        int hb = (lane << 6) + 63 - __clzll(w | 1ull);
        int low = -1;
        if (msk) low = __shfl(hb, 63 - __clzll(msk));
        l = low;
        if (lane == 0) lowA[r] = l;
        if (l < 0) break;                    // reduced to zero (never read again)
        int old = 0;
        if (lane == 0) old = atomicMin(&spiv[l], r);
        old = __shfl(old, 0);
        if (old > r) {                       // claimed; evictee reacts next pass
          if (old != INF_I && lane == 0) { int q = atomicAdd(&cnts[nxt], 1); lists[nxt][q] = old; }
          break;
        }
        // old < r: lost claim; keep chaining
      }
      if (modified && l >= 0 && lane < EW)
        g_rows[(size_t)r * EW + lane] = w;   // owner rows stored before pass barrier
    }
    __syncthreads();
    cnt = cnts[nxt];
    pass++;
  }

  // epilogue: loss1 = sum(len) - max(len) over claimed pivots
  float sum = 0.f, mx = 0.f;
  for (int l = tid; l < nE; l += 1024) {
    int r = spiv[l];
    if (r != INF_I) {
      float len = g_ef[l] - g_tf[r];
      sum += len;
      mx = fmaxf(mx, len);
    }
  }
  #pragma unroll
  for (int off = 32; off; off >>= 1) {
    sum += __shfl_xor(sum, off, 64);
    mx = fmaxf(mx, __shfl_xor(mx, off, 64));
  }
  if (lane == 0) { ssum[wave] = sum; smax[wave] = mx; }
  __syncthreads();
  if (tid == 0) {
    float S = 0.f, M = 0.f;
    for (int i = 0; i < 16; ++i) { S += ssum[i]; M = fmaxf(M, smax[i]); }
    out[0] = g_loss0 + S - M;
  }
}

extern "C" void kernel_launch(void* const* d_in, const int* in_sizes, int n_in,
                              void* d_out, int out_size, void* d_ws, size_t ws_size,
                              hipStream_t stream) {
  const float* beta = (const float*)d_in[0];
  const int*   sv   = (const int*)d_in[1];
  const int*   sd   = (const int*)d_in[2];
  const int*   bf   = (const int*)d_in[4];
  float* out = (float*)d_out;

  int nV = in_sizes[0];
  int nS = in_sizes[2];

  k_init<<<864, 256, 0, stream>>>();
  k_f<<<(nS + 255) / 256, 256, 0, stream>>>(beta, sv, sd, nS);
  k_erank<<<(MAX_E + 255) / 256, 256, 0, stream>>>(nV);
  k_trank<<<(MAX_T + 255) / 256, 256, 0, stream>>>(nV);
  k_uf<<<1, 256, 0, stream>>>(sv, nV);
  k_scatter<<<(MAX_T + 255) / 256, 256, 0, stream>>>(bf, nV);
  k_reduce<<<1, 1024, 0, stream>>>(out);
}

// Round 4
// 531.904 us; speedup vs baseline: 25.6571x; 2.4223x over previous
//
#include <hip/hip_runtime.h>
#include <stdint.h>

// Fixed 8x8x8 grid complex: nV=512, nE=2863, nT=4410, nTet=2058, nS=9843.
// Dim-1 pairs via COHOMOLOGY (coboundary delta_1) + clearing of MST edges:
// rows = edges (reverse filtration order), bits = triangles (reverse order).
// Negative (MST) edges' rows would reduce to zero -> cleared upfront.
#define MAX_S 10240
#define MAX_E 3072
#define MAX_T 4608
#define MAX_V 1024
#define TW    72     // u64 words per row >= ceil(nT/64); 2 words/lane, lanes 0..35
#define INF_I 0x7fffffff

__device__ float g_f[MAX_S];                 // filtration value per simplex (min over verts)
__device__ int   g_cnt[4];                   // simplex count per dimension
__device__ int   g_erank[MAX_E];             // edge local idx -> rank (f desc, idx asc)
__device__ float g_ef[MAX_E];                // f by edge rank
__device__ int   g_trank[MAX_T];             // tri local idx -> rank
__device__ float g_tf[MAX_T];                // f by tri rank
__device__ __attribute__((aligned(16))) unsigned long long g_rows[(size_t)MAX_E * TW];
__device__ int   g_clr[MAX_E];               // row rr -> 1 if cleared (MST edge)
__device__ float g_loss0;

__global__ void k_init() {
  size_t i = (size_t)blockIdx.x * blockDim.x + threadIdx.x;
  size_t tot = (size_t)MAX_E * TW;
  for (size_t k = i; k < tot; k += (size_t)gridDim.x * blockDim.x)
    g_rows[k] = 0ull;
  if (i < MAX_E) g_clr[i] = 0;
  if (i < 4) g_cnt[i] = 0;
}

__global__ void k_f(const float* __restrict__ beta, const int* __restrict__ sv,
                    const int* __restrict__ sd, int nS) {
  int i = blockIdx.x * blockDim.x + threadIdx.x;
  if (i >= nS) return;
  float f = beta[sv[4 * i]];
  f = fminf(f, beta[sv[4 * i + 1]]);
  f = fminf(f, beta[sv[4 * i + 2]]);
  f = fminf(f, beta[sv[4 * i + 3]]);
  g_f[i] = f;
  int d = sd[i];
  if (d >= 0 && d < 4) atomicAdd(&g_cnt[d], 1);
}

// Rank edges by (f desc, idx asc) via counting; f staged in LDS.
__global__ void __launch_bounds__(256) k_erank(int nV) {
  __shared__ float sf[MAX_E];
  int nE = g_cnt[1];
  for (int j = threadIdx.x; j < nE; j += 256) sf[j] = g_f[nV + j];
  __syncthreads();
  int i = blockIdx.x * blockDim.x + threadIdx.x;
  if (i >= nE) return;
  float fi = sf[i];
  int r = 0;
  for (int j = 0; j < nE; ++j) {
    float fj = sf[j];
    r += (fj > fi) || (fj == fi && j < i);
  }
  g_erank[i] = r;
  g_ef[r] = fi;
}

__global__ void __launch_bounds__(256) k_trank(int nV) {
  __shared__ float sf[MAX_T];
  int nE = g_cnt[1], nT = g_cnt[2];
  int base = nV + nE;
  for (int j = threadIdx.x; j < nT; j += 256) sf[j] = g_f[base + j];
  __syncthreads();
  int i = blockIdx.x * blockDim.x + threadIdx.x;
  if (i >= nT) return;
  float fi = sf[i];
  int r = 0;
  for (int j = 0; j < nT; ++j) {
    float fj = sf[j];
    r += (fj > fi) || (fj == fi && j < i);
  }
  g_trank[i] = r;
  g_tf[r] = fi;
}

// loss0 = sum_v f(v) - max_v f(v) - W(canonical max spanning tree).
// Boruvka in LDS with STRICT keys (f desc, idx asc) -> exactly the Kruskal/
// reduction-negative edge set; those edges are marked cleared for k_reduce.
__global__ void __launch_bounds__(256) k_uf(const int* __restrict__ sv, int nV) {
  __shared__ int par[MAX_V];
  __shared__ unsigned long long cand[MAX_V];
  __shared__ int hookTo[MAX_V];
  __shared__ int eu[MAX_E], ev2[MAX_E];
  __shared__ float efv[MAX_E];
  __shared__ unsigned int ekey[MAX_E];
  __shared__ int era[MAX_E];
  __shared__ float aS[4], aM[4], aW[4];
  __shared__ int nRoots;
  int tid = threadIdx.x;
  int nE = g_cnt[1];
  for (int v = tid; v < nV; v += 256) par[v] = v;
  for (int e = tid; e < nE; e += 256) {
    eu[e]  = sv[(size_t)(nV + e) * 4];
    ev2[e] = sv[(size_t)(nV + e) * 4 + 1];
    float fe = g_f[nV + e];
    efv[e] = fe;
    era[e] = g_erank[e];
    unsigned int b = __float_as_uint(fe);
    ekey[e] = (b & 0x80000000u) ? ~b : (b | 0x80000000u);  // orderable
  }
  float s = 0.f, m = -3.0e38f;
  for (int v = tid; v < nV; v += 256) { float fv = g_f[v]; s += fv; m = fmaxf(m, fv); }
  float W = 0.f;
  __syncthreads();
  for (int phase = 0; phase < 12; ++phase) {
    for (int v = tid; v < nV; v += 256) cand[v] = 0ull;
    __syncthreads();
    for (int e = tid; e < nE; e += 256) {
      int ra = eu[e];  while (par[ra] != ra) ra = par[ra];
      int rb = ev2[e]; while (par[rb] != rb) rb = par[rb];
      if (ra != rb) {
        // key: larger f wins; tie -> SMALLER edge idx wins (canonical order)
        unsigned long long key = ((unsigned long long)ekey[e] << 32)
                               | (unsigned long long)(0xffffffffu - (unsigned)e);
        atomicMax(&cand[ra], key);
        atomicMax(&cand[rb], key);
      }
    }
    __syncthreads();
    for (int v = tid; v < nV; v += 256) {
      int t = -1;
      unsigned long long cv = cand[v];
      if (par[v] == v && cv) {
        int e = (int)(0xffffffffu - (unsigned)(cv & 0xffffffffu));
        int ra = eu[e];  while (par[ra] != ra) ra = par[ra];
        int rb = ev2[e]; while (par[rb] != rb) rb = par[rb];
        int other = (ra == v) ? rb : ra;
        if (cand[other] != cv || v < other) t = other;  // break 2-cycles
      }
      hookTo[v] = t;
    }
    __syncthreads();
    for (int v = tid; v < nV; v += 256) {
      int t = hookTo[v];
      if (t >= 0) {
        par[v] = t;
        unsigned long long cv = cand[v];
        int e = (int)(0xffffffffu - (unsigned)(cv & 0xffffffffu));
        W += efv[e];
        g_clr[nE - 1 - era[e]] = 1;          // negative edge -> cleared row
      }
    }
    __syncthreads();
    for (int it = 0; it < 6; ++it) {
      for (int v = tid; v < nV; v += 256) { int p = par[v]; int gp = par[p]; if (p != gp) par[v] = gp; }
      __syncthreads();
    }
    if (tid == 0) nRoots = 0;
    __syncthreads();
    int loc = 0;
    for (int v = tid; v < nV; v += 256) loc += (par[v] == v);
    atomicAdd(&nRoots, loc);
    __syncthreads();
    if (nRoots <= 1) break;
    __syncthreads();
  }
  int lane = tid & 63, wave = tid >> 6;
  #pragma unroll
  for (int off = 32; off; off >>= 1) {
    s += __shfl_xor(s, off, 64);
    m = fmaxf(m, __shfl_xor(m, off, 64));
    W += __shfl_xor(W, off, 64);
  }
  if (lane == 0) { aS[wave] = s; aM[wave] = m; aW[wave] = W; }
  __syncthreads();
  if (tid == 0) {
    float S = 0.f, M = -3.0e38f, WW = 0.f;
    for (int i = 0; i < 4; ++i) { S += aS[i]; M = fmaxf(M, aM[i]); WW += aW[i]; }
    g_loss0 = S - M - WW;
  }
}

// Build coboundary rows: for each triangle t, set bit (nT-1-trank[t]) in the
// row of each of its 3 edges (row index nE-1-erank[e]).
__global__ void k_scatter(const int* __restrict__ bf, int nV) {
  int nE = g_cnt[1], nT = g_cnt[2];
  int t = blockIdx.x * blockDim.x + threadIdx.x;
  if (t >= nT) return;
  int lpos = nT - 1 - g_trank[t];
  size_t base = (size_t)2 * nE + (size_t)3 * t;
  unsigned long long bit = 1ull << (lpos & 63);
  int word = lpos >> 6;
  for (int j = 0; j < 3; ++j) {
    int e = bf[base + j] - nV;
    int rr = nE - 1 - g_erank[e];
    atomicOr(&g_rows[(size_t)rr * TW + word], bit);
  }
}

__device__ __forceinline__ int row_low(unsigned long long x, unsigned long long y, int lane) {
  unsigned long long msk = __ballot((x | y) != 0ull);
  int hb = y ? (lane * 128 + 127 - __clzll(y)) : (lane * 128 + 63 - __clzll(x | 1ull));
  return msk ? __shfl(hb, 63 - __clzll(msk)) : -1;
}

// delta_1 reduction, lock-free with active lists (machinery validated R2/R3).
// Cleared rows never claim and are never read. Every surviving row ends with
// a distinct pivot (positive edges all die; b1 = 0).
__global__ void __launch_bounds__(1024) k_reduce(float* __restrict__ out) {
  __shared__ int spiv[MAX_T];       // tri position -> owning edge row (or INF)
  __shared__ int lowA[MAX_E];
  __shared__ int stamp[MAX_E];
  __shared__ int lists[2][MAX_E];
  __shared__ int cnts[2];
  __shared__ int workIdx;
  __shared__ float ssum[16], smax[16];

  int tid = threadIdx.x;
  int lane = tid & 63;
  int wave = tid >> 6;
  int nE = g_cnt[1], nT = g_cnt[2];

  for (int i = tid; i < nT; i += 1024) spiv[i] = INF_I;
  for (int r = tid; r < nE; r += 1024) stamp[r] = -1;
  if (tid == 0) { cnts[0] = 0; cnts[1] = 0; }
  __syncthreads();

  // initial lows + claims
  for (int r = wave; r < nE; r += 16) {
    if (g_clr[r]) { if (lane == 0) lowA[r] = -1; continue; }
    unsigned long long wx = 0, wy = 0;
    if (lane < 36) {
      const ulonglong2* q = (const ulonglong2*)&g_rows[(size_t)r * TW + 2 * lane];
      ulonglong2 v = *q; wx = v.x; wy = v.y;
    }
    int low = row_low(wx, wy, lane);
    if (lane == 0) { lowA[r] = low; if (low >= 0) atomicMin(&spiv[low], r); }
  }
  __syncthreads();
  for (int r = tid; r < nE; r += 1024) {
    int l = lowA[r];
    if (l >= 0 && spiv[l] != r) { int q = atomicAdd(&cnts[0], 1); lists[0][q] = r; }
  }
  __syncthreads();

  int pass = 0;
  int cnt = cnts[0];
  while (cnt > 0 && pass < 50000) {
    int cur = pass & 1, nxt = cur ^ 1;
    if (tid == 0) { cnts[nxt] = 0; workIdx = 0; }
    for (int i = tid; i < cnt; i += 1024) stamp[lists[cur][i]] = pass;
    __syncthreads();
    for (;;) {
      int idx = 0;
      if (lane == 0) idx = atomicAdd(&workIdx, 1);
      idx = __shfl(idx, 0);
      if (idx >= cnt) break;
      int r = lists[cur][idx];
      int l = lowA[r];                       // >= 0 for every listed row
      unsigned long long wx = 0, wy = 0;
      bool loaded = false, modified = false;
      for (;;) {
        int p = spiv[l];                     // p < r always
        // prefetch winner's row; discarded if stamped (torn reads never used)
        unsigned long long px = 0, py = 0;
        if (lane < 36) {
          const ulonglong2* q = (const ulonglong2*)&g_rows[(size_t)p * TW + 2 * lane];
          ulonglong2 v = *q; px = v.x; py = v.y;
        }
        if (stamp[p] == pass) {              // winner busy this pass -> retry next
          if (lane == 0) { int q = atomicAdd(&cnts[nxt], 1); lists[nxt][q] = r; }
          break;
        }
        if (!loaded) {
          if (lane < 36) {
            const ulonglong2* q = (const ulonglong2*)&g_rows[(size_t)r * TW + 2 * lane];
            ulonglong2 v = *q; wx = v.x; wy = v.y;
          }
          loaded = true;
        }
        wx ^= px; wy ^= py;
        modified = true;
        l = row_low(wx, wy, lane);
        if (lane == 0) lowA[r] = l;
        if (l < 0) break;                    // theory: unreachable for uncleared rows
        int old = 0;
        if (lane == 0) old = atomicMin(&spiv[l], r);
        old = __shfl(old, 0);
        if (old > r) {                       // claimed; evictee reacts next pass
          if (old != INF_I && lane == 0) { int q = atomicAdd(&cnts[nxt], 1); lists[nxt][q] = old; }
          break;
        }
        // old < r: lost claim; keep chaining
      }
      if (modified && l >= 0 && lane < 36) {
        ulonglong2* q = (ulonglong2*)&g_rows[(size_t)r * TW + 2 * lane];
        ulonglong2 v; v.x = wx; v.y = wy; *q = v;
      }
    }
    __syncthreads();
    cnt = cnts[nxt];
    pass++;
  }

  // epilogue: pair (edge rank nE-1-r, tri rank nT-1-l); loss1 = sum - max
  float sum = 0.f, mx = 0.f;
  for (int l = tid; l < nT; l += 1024) {
    int r = spiv[l];
    if (r != INF_I) {
      float len = g_ef[nE - 1 - r] - g_tf[nT - 1 - l];
      sum += len;
      mx = fmaxf(mx, len);
    }
  }
  #pragma unroll
  for (int off = 32; off; off >>= 1) {
    sum += __shfl_xor(sum, off, 64);
    mx = fmaxf(mx, __shfl_xor(mx, off, 64));
  }
  if (lane == 0) { ssum[wave] = sum; smax[wave] = mx; }
  __syncthreads();
  if (tid == 0) {
    float S = 0.f, M = 0.f;
    for (int i = 0; i < 16; ++i) { S += ssum[i]; M = fmaxf(M, smax[i]); }
    out[0] = g_loss0 + S - M;
  }
}

extern "C" void kernel_launch(void* const* d_in, const int* in_sizes, int n_in,
                              void* d_out, int out_size, void* d_ws, size_t ws_size,
                              hipStream_t stream) {
  const float* beta = (const float*)d_in[0];
  const int*   sv   = (const int*)d_in[1];
  const int*   sd   = (const int*)d_in[2];
  const int*   bf   = (const int*)d_in[4];
  float* out = (float*)d_out;

  int nV = in_sizes[0];
  int nS = in_sizes[2];

  k_init<<<864, 256, 0, stream>>>();
  k_f<<<(nS + 255) / 256, 256, 0, stream>>>(beta, sv, sd, nS);
  k_erank<<<(MAX_E + 255) / 256, 256, 0, stream>>>(nV);
  k_trank<<<(MAX_T + 255) / 256, 256, 0, stream>>>(nV);
  k_uf<<<1, 256, 0, stream>>>(sv, nV);
  k_scatter<<<(MAX_T + 255) / 256, 256, 0, stream>>>(bf, nV);
  k_reduce<<<1, 1024, 0, stream>>>(out);
}

// Round 5
// 296.730 us; speedup vs baseline: 45.9918x; 1.7926x over previous
//
#include <hip/hip_runtime.h>
#include <stdint.h>

// Fixed 8x8x8 grid complex: nV=512, nE=2863, nT=4410, nTet=2058, nS=9843.
// Dim-1 pairs via COHOMOLOGY (coboundary delta_1) + clearing of MST edges:
// rows = edges (reverse filtration order), bits = triangles (reverse order).
// Negative (MST) edges' rows would reduce to zero -> cleared upfront.
#define MAX_S 10240
#define MAX_E 3072
#define MAX_T 4608
#define MAX_V 1024
#define TW    72     // u64 words per row >= ceil(nT/64); 2 words/lane, lanes 0..35
#define INF_I 0x7fffffff
#define EBLK  12     // ceil(MAX_E/256)
#define TBLK  18     // ceil(MAX_T/256)

__device__ float g_f[MAX_S];                 // filtration value per simplex (min over verts)
__device__ int   g_erank[MAX_E];             // edge local idx -> rank (f desc, idx asc)
__device__ float g_ef[MAX_E];                // f by edge rank
__device__ int   g_trank[MAX_T];             // tri local idx -> rank
__device__ float g_tf[MAX_T];                // f by tri rank
__device__ __attribute__((aligned(16))) unsigned long long g_rows[(size_t)MAX_E * TW];
__device__ int   g_clr[MAX_E];               // row rr -> 1 if cleared (MST edge)
__device__ float g_loss0;

// sd is sorted (verts, edges, tris, tets): first index with dim > d.
__device__ __forceinline__ int ub_dim(const int* __restrict__ sd, int nS, int d) {
  int lo = 0, hi = nS;
  while (lo < hi) { int mid = (lo + hi) >> 1; if (sd[mid] <= d) lo = mid + 1; else hi = mid; }
  return lo;
}

// Fused: clear g_rows/g_clr + compute f (min over verts). Independent tasks.
__global__ void k_prep(const float* __restrict__ beta, const int* __restrict__ sv, int nS) {
  size_t i = (size_t)blockIdx.x * blockDim.x + threadIdx.x;
  size_t stride = (size_t)gridDim.x * blockDim.x;
  for (size_t k = i; k < (size_t)MAX_E * TW; k += stride) g_rows[k] = 0ull;
  for (size_t k = i; k < MAX_E; k += stride) g_clr[k] = 0;
  for (size_t k = i; k < (size_t)nS; k += stride) {
    float f = beta[sv[4 * k]];
    f = fminf(f, beta[sv[4 * k + 1]]);
    f = fminf(f, beta[sv[4 * k + 2]]);
    f = fminf(f, beta[sv[4 * k + 3]]);
    g_f[k] = f;
  }
}

// Fused rank kernel: blocks [0,EBLK) rank edges, [EBLK,EBLK+TBLK) rank tris.
// Rank by (f desc, idx asc) via counting; f staged in LDS (broadcast reads).
__global__ void __launch_bounds__(256) k_rank(const int* __restrict__ sd, int nV, int nS) {
  __shared__ float sf[MAX_T];
  int nE = ub_dim(sd, nS, 1) - nV;
  if (blockIdx.x < EBLK) {
    for (int j = threadIdx.x; j < nE; j += 256) sf[j] = g_f[nV + j];
    __syncthreads();
    int i = blockIdx.x * 256 + threadIdx.x;
    if (i >= nE) return;
    float fi = sf[i];
    int r = 0;
    for (int j = 0; j < nE; ++j) {
      float fj = sf[j];
      r += (fj > fi) || (fj == fi && j < i);
    }
    g_erank[i] = r;
    g_ef[r] = fi;
  } else {
    int nT = ub_dim(sd, nS, 2) - nV - nE;
    int base = nV + nE;
    for (int j = threadIdx.x; j < nT; j += 256) sf[j] = g_f[base + j];
    __syncthreads();
    int i = (blockIdx.x - EBLK) * 256 + threadIdx.x;
    if (i >= nT) return;
    float fi = sf[i];
    int r = 0;
    for (int j = 0; j < nT; ++j) {
      float fj = sf[j];
      r += (fj > fi) || (fj == fi && j < i);
    }
    g_trank[i] = r;
    g_tf[r] = fi;
  }
}

// Fused: block 0 = Boruvka UF (loss0 + clearing marks); blocks 1.. = scatter
// coboundary rows. Disjoint outputs (g_clr/g_loss0 vs g_rows).
__global__ void __launch_bounds__(256) k_ufsc(const int* __restrict__ sv,
                                              const int* __restrict__ bf,
                                              const int* __restrict__ sd,
                                              int nV, int nS) {
  __shared__ int par[MAX_V];
  __shared__ unsigned long long cand[MAX_V];
  __shared__ int hookTo[MAX_V];
  __shared__ int eu[MAX_E], ev2[MAX_E];
  __shared__ float efv[MAX_E];
  __shared__ unsigned int ekey[MAX_E];
  __shared__ int era[MAX_E];
  __shared__ unsigned short alive[2][MAX_E];
  __shared__ int nNext;
  __shared__ float aS[4], aM[4], aW[4];
  int tid = threadIdx.x;
  int nE = ub_dim(sd, nS, 1) - nV;

  if (blockIdx.x != 0) {
    // ---- scatter role: build coboundary rows ----
    int nT = ub_dim(sd, nS, 2) - nV - nE;
    int t = (blockIdx.x - 1) * 256 + tid;
    if (t >= nT) return;
    int lpos = nT - 1 - g_trank[t];
    size_t base = (size_t)2 * nE + (size_t)3 * t;
    unsigned long long bit = 1ull << (lpos & 63);
    int word = lpos >> 6;
    for (int j = 0; j < 3; ++j) {
      int e = bf[base + j] - nV;
      int rr = nE - 1 - g_erank[e];
      atomicOr(&g_rows[(size_t)rr * TW + word], bit);
    }
    return;
  }

  // ---- UF role: loss0 = sum_v f(v) - max_v f(v) - W(canonical max ST).
  // Boruvka with STRICT keys (f desc, idx asc) == Kruskal's negative edge set;
  // alive-list compaction: only cross edges survive to the next phase.
  for (int v = tid; v < nV; v += 256) par[v] = v;
  for (int e = tid; e < nE; e += 256) {
    eu[e]  = sv[(size_t)(nV + e) * 4];
    ev2[e] = sv[(size_t)(nV + e) * 4 + 1];
    float fe = g_f[nV + e];
    efv[e] = fe;
    era[e] = g_erank[e];
    unsigned int b = __float_as_uint(fe);
    ekey[e] = (b & 0x80000000u) ? ~b : (b | 0x80000000u);  // orderable
    alive[0][e] = (unsigned short)e;
  }
  float s = 0.f, m = -3.0e38f;
  for (int v = tid; v < nV; v += 256) { float fv = g_f[v]; s += fv; m = fmaxf(m, fv); }
  float W = 0.f;
  int nAlive = nE, cur = 0;
  __syncthreads();
  for (int phase = 0; phase < 20 && nAlive > 0; ++phase) {
    for (int v = tid; v < nV; v += 256) cand[v] = 0ull;
    if (tid == 0) nNext = 0;
    __syncthreads();
    for (int i = tid; i < nAlive; i += 256) {
      int e = alive[cur][i];
      int ra = eu[e];  while (par[ra] != ra) ra = par[ra];
      int rb = ev2[e]; while (par[rb] != rb) rb = par[rb];
      if (ra != rb) {
        int q = atomicAdd(&nNext, 1);
        alive[cur ^ 1][q] = (unsigned short)e;
        // key: larger f wins; tie -> SMALLER edge idx wins (canonical order)
        unsigned long long key = ((unsigned long long)ekey[e] << 32)
                               | (unsigned long long)(0xffffffffu - (unsigned)e);
        atomicMax(&cand[ra], key);
        atomicMax(&cand[rb], key);
      }
    }
    __syncthreads();
    for (int v = tid; v < nV; v += 256) {
      int t = -1;
      unsigned long long cv = cand[v];
      if (par[v] == v && cv) {
        int e = (int)(0xffffffffu - (unsigned)(cv & 0xffffffffu));
        int ra = eu[e];  while (par[ra] != ra) ra = par[ra];
        int rb = ev2[e]; while (par[rb] != rb) rb = par[rb];
        int other = (ra == v) ? rb : ra;
        if (cand[other] != cv || v < other) t = other;  // break 2-cycles
      }
      hookTo[v] = t;
    }
    __syncthreads();
    for (int v = tid; v < nV; v += 256) {
      int t = hookTo[v];
      if (t >= 0) {
        par[v] = t;
        int e = (int)(0xffffffffu - (unsigned)(cand[v] & 0xffffffffu));
        W += efv[e];
        g_clr[nE - 1 - era[e]] = 1;          // negative edge -> cleared row
      }
    }
    __syncthreads();
    for (int it = 0; it < 5; ++it) {
      for (int v = tid; v < nV; v += 256) { int p = par[v]; int gp = par[p]; if (p != gp) par[v] = gp; }
      __syncthreads();
    }
    nAlive = nNext;
    cur ^= 1;
    __syncthreads();                          // nNext read-before-reset fence
  }
  int lane = tid & 63, wave = tid >> 6;
  #pragma unroll
  for (int off = 32; off; off >>= 1) {
    s += __shfl_xor(s, off, 64);
    m = fmaxf(m, __shfl_xor(m, off, 64));
    W += __shfl_xor(W, off, 64);
  }
  if (lane == 0) { aS[wave] = s; aM[wave] = m; aW[wave] = W; }
  __syncthreads();
  if (tid == 0) {
    float S = 0.f, M = -3.0e38f, WW = 0.f;
    for (int i = 0; i < 4; ++i) { S += aS[i]; M = fmaxf(M, aM[i]); WW += aW[i]; }
    g_loss0 = S - M - WW;
  }
}

__device__ __forceinline__ int row_low(unsigned long long x, unsigned long long y, int lane) {
  unsigned long long msk = __ballot((x | y) != 0ull);
  int hb = y ? (lane * 128 + 127 - __clzll(y)) : (lane * 128 + 63 - __clzll(x | 1ull));
  return msk ? __shfl(hb, 63 - __clzll(msk)) : -1;
}

// delta_1 reduction, lock-free with active lists. Cleared rows never claim
// and are never read. Every surviving row ends with a distinct pivot.
__global__ void __launch_bounds__(1024) k_reduce(const int* __restrict__ sd,
                                                 int nV, int nS,
                                                 float* __restrict__ out) {
  __shared__ int spiv[MAX_T];       // tri position -> owning edge row (or INF)
  __shared__ int lowA[MAX_E];
  __shared__ int stamp[MAX_E];
  __shared__ int lists[2][MAX_E];
  __shared__ int cnts[2];
  __shared__ int workIdx;
  __shared__ float ssum[16], smax[16];

  int tid = threadIdx.x;
  int lane = tid & 63;
  int wave = tid >> 6;
  int nE = ub_dim(sd, nS, 1) - nV;
  int nT = ub_dim(sd, nS, 2) - nV - nE;

  for (int i = tid; i < nT; i += 1024) spiv[i] = INF_I;
  for (int r = tid; r < nE; r += 1024) stamp[r] = -1;
  if (tid == 0) { cnts[0] = 0; cnts[1] = 0; }
  __syncthreads();

  // initial lows + claims (two rows in flight per wave to hide L2 latency)
  for (int r = wave; r < nE; r += 32) {
    int r2 = r + 16;
    bool h2 = (r2 < nE);
    int c1 = g_clr[r];
    int c2 = h2 ? g_clr[r2] : 1;
    unsigned long long ax = 0, ay = 0, bx = 0, by = 0;
    if (!c1 && lane < 36) {
      ulonglong2 v = *(const ulonglong2*)&g_rows[(size_t)r * TW + 2 * lane];
      ax = v.x; ay = v.y;
    }
    if (!c2 && lane < 36) {
      ulonglong2 v = *(const ulonglong2*)&g_rows[(size_t)r2 * TW + 2 * lane];
      bx = v.x; by = v.y;
    }
    int low1 = c1 ? -1 : row_low(ax, ay, lane);
    if (lane == 0) { lowA[r] = low1; if (low1 >= 0) atomicMin(&spiv[low1], r); }
    if (h2) {
      int low2 = c2 ? -1 : row_low(bx, by, lane);
      if (lane == 0) { lowA[r2] = low2; if (low2 >= 0) atomicMin(&spiv[low2], r2); }
    }
  }
  __syncthreads();
  for (int r = tid; r < nE; r += 1024) {
    int l = lowA[r];
    if (l >= 0 && spiv[l] != r) { int q = atomicAdd(&cnts[0], 1); lists[0][q] = r; }
  }
  __syncthreads();

  int pass = 0;
  int cnt = cnts[0];
  while (cnt > 0 && pass < 50000) {
    int cur = pass & 1, nxt = cur ^ 1;
    if (tid == 0) { cnts[nxt] = 0; workIdx = 0; }
    for (int i = tid; i < cnt; i += 1024) stamp[lists[cur][i]] = pass;
    __syncthreads();
    for (;;) {
      int idx = 0;
      if (lane == 0) idx = atomicAdd(&workIdx, 1);
      idx = __shfl(idx, 0);
      if (idx >= cnt) break;
      int r = lists[cur][idx];
      int l = lowA[r];                       // >= 0 for every listed row
      unsigned long long wx = 0, wy = 0;
      bool loaded = false, modified = false;
      for (;;) {
        int p = spiv[l];                     // p < r always
        // prefetch winner's row; discarded if stamped (torn reads never used)
        unsigned long long px = 0, py = 0;
        if (lane < 36) {
          ulonglong2 v = *(const ulonglong2*)&g_rows[(size_t)p * TW + 2 * lane];
          px = v.x; py = v.y;
        }
        if (stamp[p] == pass) {              // winner busy this pass -> retry next
          if (lane == 0) { int q = atomicAdd(&cnts[nxt], 1); lists[nxt][q] = r; }
          break;
        }
        if (!loaded) {
          if (lane < 36) {
            ulonglong2 v = *(const ulonglong2*)&g_rows[(size_t)r * TW + 2 * lane];
            wx = v.x; wy = v.y;
          }
          loaded = true;
        }
        wx ^= px; wy ^= py;
        modified = true;
        l = row_low(wx, wy, lane);
        if (lane == 0) lowA[r] = l;
        if (l < 0) break;                    // unreachable for uncleared rows
        int old = 0;
        if (lane == 0) old = atomicMin(&spiv[l], r);
        old = __shfl(old, 0);
        if (old > r) {                       // claimed; evictee reacts next pass
          if (old != INF_I && lane == 0) { int q = atomicAdd(&cnts[nxt], 1); lists[nxt][q] = old; }
          break;
        }
        // old < r: lost claim; keep chaining
      }
      if (modified && l >= 0 && lane < 36) {
        ulonglong2 v; v.x = wx; v.y = wy;
        *(ulonglong2*)&g_rows[(size_t)r * TW + 2 * lane] = v;
      }
    }
    __syncthreads();
    cnt = cnts[nxt];
    pass++;
  }

  // epilogue: pair (edge rank nE-1-r, tri rank nT-1-l); loss1 = sum - max
  float sum = 0.f, mx = 0.f;
  for (int l = tid; l < nT; l += 1024) {
    int r = spiv[l];
    if (r != INF_I) {
      float len = g_ef[nE - 1 - r] - g_tf[nT - 1 - l];
      sum += len;
      mx = fmaxf(mx, len);
    }
  }
  #pragma unroll
  for (int off = 32; off; off >>= 1) {
    sum += __shfl_xor(sum, off, 64);
    mx = fmaxf(mx, __shfl_xor(mx, off, 64));
  }
  if (lane == 0) { ssum[wave] = sum; smax[wave] = mx; }
  __syncthreads();
  if (tid == 0) {
    float S = 0.f, M = 0.f;
    for (int i = 0; i < 16; ++i) { S += ssum[i]; M = fmaxf(M, smax[i]); }
    out[0] = g_loss0 + S - M;
  }
}

extern "C" void kernel_launch(void* const* d_in, const int* in_sizes, int n_in,
                              void* d_out, int out_size, void* d_ws, size_t ws_size,
                              hipStream_t stream) {
  const float* beta = (const float*)d_in[0];
  const int*   sv   = (const int*)d_in[1];
  const int*   sd   = (const int*)d_in[2];
  const int*   bf   = (const int*)d_in[4];
  float* out = (float*)d_out;

  int nV = in_sizes[0];
  int nS = in_sizes[2];

  k_prep<<<512, 256, 0, stream>>>(beta, sv, nS);
  k_rank<<<EBLK + TBLK, 256, 0, stream>>>(sd, nV, nS);
  k_ufsc<<<1 + TBLK, 256, 0, stream>>>(sv, bf, sd, nV, nS);
  k_reduce<<<1, 1024, 0, stream>>>(sd, nV, nS, out);
}